// Round 1
// baseline (332.212 us; speedup 1.0000x reference)
//
#include <hip/hip_runtime.h>
#include <stdint.h>

#define B_    4
#define N_    2048
#define D_    4096
#define E_    64
#define TOKENS (B_ * N_)        // 8192
#define KT    32                // K-tile staged in LDS
#define TTOK  32                // tokens per block tile

// ---------------------------------------------------------------------------
// K1: split-K fp32 GEMM  logits_partial[kc][tok][e] = A[tok,:]@W[:,e] over chunk
// block = 128 threads, tile = 32 tokens x 64 experts, thread tile 4x4.
// A staged transposed in LDS (As[kk][tok], pitch 36 keeps float4 alignment and
// breaks the 32-bank stride); W staged as-is (rows of 64 are coalesced).
// ---------------------------------------------------------------------------
__global__ __launch_bounds__(128) void k_gemm(const float* __restrict__ A,
                                              const float* __restrict__ W,
                                              float* __restrict__ P,
                                              int kchunk) {
    __shared__ float As[KT][TTOK + 4];   // [kk][tok], pitch 36 (16B-aligned rows)
    __shared__ float Ws[KT][E_];         // [kk][e]

    const int tid  = threadIdx.x;
    const int tt   = blockIdx.x;          // token tile
    const int kc   = blockIdx.y;          // k chunk
    const int tok0 = tt * TTOK;
    const int kbase = kc * kchunk;

    const int t0 = (tid & 7) * 4;         // token offset within tile (0..28)
    const int e0 = (tid >> 3) * 4;        // expert offset (0..60)

    float acc[4][4] = {{0.f}};

    for (int kt = 0; kt < kchunk; kt += KT) {
        // ---- stage A transposed: global coalesced along k, LDS write strided
        {
            const int kk = tid & 31;
            const int tb = tid >> 5;       // 0..3
            const float* ga = A + (size_t)tok0 * D_ + (size_t)(kbase + kt) + kk;
            #pragma unroll
            for (int i = 0; i < 8; ++i) {
                const int tok = tb + i * 4;
                As[kk][tok] = ga[(size_t)tok * D_];
            }
        }
        // ---- stage W: rows of 64 floats, float4 coalesced
        {
            const int e4 = (tid & 15) * 4;
            const int kb = tid >> 4;       // 0..7
            #pragma unroll
            for (int i = 0; i < 4; ++i) {
                const int kk = kb + i * 8;
                const float4 v = *reinterpret_cast<const float4*>(
                    &W[(size_t)(kbase + kt + kk) * E_ + e4]);
                *reinterpret_cast<float4*>(&Ws[kk][e4]) = v;
            }
        }
        __syncthreads();

        #pragma unroll
        for (int kk = 0; kk < KT; ++kk) {
            const float4 a = *reinterpret_cast<const float4*>(&As[kk][t0]);
            const float4 b = *reinterpret_cast<const float4*>(&Ws[kk][e0]);
            acc[0][0] += a.x * b.x; acc[0][1] += a.x * b.y;
            acc[0][2] += a.x * b.z; acc[0][3] += a.x * b.w;
            acc[1][0] += a.y * b.x; acc[1][1] += a.y * b.y;
            acc[1][2] += a.y * b.z; acc[1][3] += a.y * b.w;
            acc[2][0] += a.z * b.x; acc[2][1] += a.z * b.y;
            acc[2][2] += a.z * b.z; acc[2][3] += a.z * b.w;
            acc[3][0] += a.w * b.x; acc[3][1] += a.w * b.y;
            acc[3][2] += a.w * b.z; acc[3][3] += a.w * b.w;
        }
        __syncthreads();
    }

    float* base = P + ((size_t)kc * TOKENS + tok0) * E_;
    #pragma unroll
    for (int i = 0; i < 4; ++i) {
        float4 v = make_float4(acc[i][0], acc[i][1], acc[i][2], acc[i][3]);
        *reinterpret_cast<float4*>(&base[(size_t)(t0 + i) * E_ + e0]) = v;
    }
}

// ---------------------------------------------------------------------------
// K2: reduce split-K partials, per-token softmax stats (wave per token).
// lane = expert. Outputs: argmax idx, gate=maxprob, z contribution, prob sums.
// ---------------------------------------------------------------------------
__global__ __launch_bounds__(256) void k_softmax(const float* __restrict__ P,
                                                 int* __restrict__ idx,
                                                 float* __restrict__ gate,
                                                 float* __restrict__ probsum,
                                                 float* __restrict__ zbins,
                                                 int ks) {
    const int tid  = threadIdx.x;
    const int wid  = tid >> 6;
    const int lane = tid & 63;
    const int tok  = blockIdx.x * 4 + wid;

    float l = 0.f;
    for (int kc = 0; kc < ks; ++kc)
        l += P[((size_t)kc * TOKENS + tok) * E_ + lane];

    // wave argmax (first-index tie-break, matches numpy)
    float m = l; int mi = lane;
    #pragma unroll
    for (int off = 32; off > 0; off >>= 1) {
        const float om = __shfl_down(m, off);
        const int   oi = __shfl_down(mi, off);
        if (om > m || (om == m && oi < mi)) { m = om; mi = oi; }
    }
    m  = __shfl(m, 0);
    mi = __shfl(mi, 0);

    const float p = __expf(l - m);
    float s = p;
    #pragma unroll
    for (int off = 32; off > 0; off >>= 1) s += __shfl_down(s, off);
    s = __shfl(s, 0);

    const float prob = p / s;

    __shared__ float pacc[4][E_];
    __shared__ float zv[4];
    pacc[wid][lane] = prob;
    if (lane == 0) {
        const float lse = m + logf(s);
        zv[wid]   = lse * lse;
        idx[tok]  = mi;
        gate[tok] = 1.0f / s;   // exp(m-m)/s = max prob
    }
    __syncthreads();

    if (tid < E_) {
        const float ps = pacc[0][tid] + pacc[1][tid] + pacc[2][tid] + pacc[3][tid];
        const int b = (blockIdx.x * 4) / N_;   // block never crosses batch
        atomicAdd(&probsum[b * E_ + tid], ps);
    }
    if (tid == 0)
        atomicAdd(&zbins[blockIdx.x & 63], zv[0] + zv[1] + zv[2] + zv[3]);
}

// ---------------------------------------------------------------------------
// K3: ordered position-in-expert via wave ballot. One wave per (b,e).
// Matches the reference cumsum exactly (token order).
// ---------------------------------------------------------------------------
__global__ __launch_bounds__(64) void k_pos(const int* __restrict__ idx,
                                            int* __restrict__ pos,
                                            int* __restrict__ counts) {
    const int b = blockIdx.x >> 6;
    const int e = blockIdx.x & 63;
    const int lane = threadIdx.x;
    const int* ib = idx + b * N_;
    int running = 0;
    for (int step = 0; step < N_ / 64; ++step) {
        const int t = step * 64 + lane;
        const bool match = (ib[t] == e);
        const unsigned long long mask = __ballot(match);
        if (match)
            pos[b * N_ + t] = running + __popcll(mask & ((1ull << lane) - 1ull));
        running += __popcll(mask);
    }
    if (lane == 0) counts[b * E_ + e] = running;
}

// ---------------------------------------------------------------------------
// K4: loss scalars.  aux = sum(count*probsum) / 262144 ;  z = sum(zbins)/8192
// ---------------------------------------------------------------------------
__global__ __launch_bounds__(256) void k_loss(const int* __restrict__ counts,
                                              const float* __restrict__ probsum,
                                              const float* __restrict__ zbins,
                                              float* __restrict__ out_aux,
                                              float* __restrict__ out_z) {
    __shared__ float red[256];
    const int tid = threadIdx.x;
    red[tid] = (float)counts[tid] * probsum[tid];
    __syncthreads();
    for (int off = 128; off > 0; off >>= 1) {
        if (tid < off) red[tid] += red[tid + off];
        __syncthreads();
    }
    if (tid == 0) {
        // E^2 / (B*E*N*N) = 4096 / (4*64*2048*2048) = 1/262144
        *out_aux = red[0] * (1.0f / 262144.0f);
        float z = 0.f;
        for (int i = 0; i < 64; ++i) z += zbins[i];
        *out_z = z / (float)TOKENS;
    }
}

// ---------------------------------------------------------------------------
// K5: scatter the <=8192 nonzeros into the (pre-zeroed) dispatch/combine.
// ---------------------------------------------------------------------------
__global__ __launch_bounds__(256) void k_scatter(const int* __restrict__ idx,
                                                 const int* __restrict__ pos,
                                                 const float* __restrict__ gate,
                                                 float* __restrict__ out,
                                                 int C, size_t half) {
    const int t = blockIdx.x * 256 + threadIdx.x;
    if (t >= TOKENS) return;
    const int p = pos[t];
    if (p < C) {
        const size_t off = (size_t)t * E_ * C + (size_t)idx[t] * C + p;
        out[off] = 1.0f;
        out[half + off] = gate[t];
    }
}

// ---------------------------------------------------------------------------
extern "C" void kernel_launch(void* const* d_in, const int* in_sizes, int n_in,
                              void* d_out, int out_size, void* d_ws, size_t ws_size,
                              hipStream_t stream) {
    const float* A = (const float*)d_in[0];
    const float* W = (const float*)d_in[1];
    float* out = (float*)d_out;

    // capacity from output shape: (out_size-2)/2 = TOKENS*E*C
    const size_t half = ((size_t)out_size - 2) / 2;
    const int C = (int)(half / ((size_t)TOKENS * E_));   // 40

    // pick largest split-K whose partials fit in ws (deterministic per session)
    int ks = 8;
    auto need = [](int k) {
        return ((size_t)k * TOKENS * E_ + 3 * TOKENS + 2 * B_ * E_ + 64) * 4;
    };
    while (ks > 1 && need(ks) > ws_size) ks >>= 1;
    const int kchunk = D_ / ks;

    // ws carve (floats)
    float* P = (float*)d_ws;
    size_t off = (size_t)ks * TOKENS * E_;
    int*   idx     = (int*)(P + off);   off += TOKENS;
    int*   pos     = (int*)(P + off);   off += TOKENS;
    float* gate    = P + off;           off += TOKENS;
    float* probsum = P + off;           off += B_ * E_;
    float* zbins   = P + off;           off += 64;
    int*   counts  = (int*)(P + off);   off += B_ * E_;

    // zero outputs (mostly-zero tensors) and the atomic accumulators
    hipMemsetAsync(d_out, 0, (size_t)out_size * sizeof(float), stream);
    hipMemsetAsync(probsum, 0, (B_ * E_ + 64) * sizeof(float), stream);

    k_gemm<<<dim3(TOKENS / TTOK, ks), 128, 0, stream>>>(A, W, P, kchunk);
    k_softmax<<<TOKENS / 4, 256, 0, stream>>>(P, idx, gate, probsum, zbins, ks);
    k_pos<<<B_ * E_, 64, 0, stream>>>(idx, pos, counts);
    k_loss<<<1, 256, 0, stream>>>(counts, probsum, zbins,
                                  out + 2 * half, out + 2 * half + 1);
    k_scatter<<<(TOKENS + 255) / 256, 256, 0, stream>>>(idx, pos, gate, out, C, half);
}